// Round 11
// baseline (138.493 us; speedup 1.0000x reference)
//
#include <hip/hip_runtime.h>
#include <hip/hip_bf16.h>
#include <stdint.h>

// ---------------------------------------------------------------------------
// MappingNetwork: backbone 4x(Linear+ReLU) [16->128, 3x 128->128], then the
// selected expert head only (4 layers, last no-ReLU, 128->64).
//
// Round-21: BARRIER-FREE L2-DIRECT WEIGHT STREAMING (catalog mistake #7).
// r20 post-mortem: half-layer phases regressed (-2us) -> phase count is not
// the driver; the barrier-schedule family (r16-r20) is exhausted at fused
// ~34us. Root premise re-examined: after r19's single-f16 weights the WHOLE
// weight set is 1.94MB (324KB per XCD with the swizzle) -- L2-resident.
// LDS staging of L2-fit data is pure overhead: the stage+barrier scaffolding
// costs ~20us of the 34 while protecting an 11us LDS-read floor that global
// L2 reads match anyway (212KB/wave x 2048 waves = 434MB / 36.9TB/s ~ 12us).
// Fix: weights read DIRECTLY from global (memory layout == consumption
// order, same b128-shaped loads); no LDS, no __syncthreads, no dbuf; 1-wave
// blocks (64 thr, 32 samples), NBLK=2304 -> ~2048 live waves = 8 balanced
// waves/CU (also fixes the 2.25-block/CU imbalance). Latency: 32 indep
// loads/layer ILP x 8 waves TLP >> ~200cyc L2 latency. Zero race surface.
//
// Kept from r19 (verified, 130.8us): single-term f16 weights (absmax
// 1.5259e-5, 4x margin vs 6.226e-5 threshold); M=32/wave acts-in-registers;
// permlane32_swap epilogue (pure VALU, HW-verified D->B fragment layouts);
// setprio around MFMA (independent-wave regime = T5's positive case);
// XCD-chunked bijective swizzle (2304%8==0); CAP=4608 idxb scheme;
// prep_scatter unchanged.
// ---------------------------------------------------------------------------

typedef _Float16 f16;
typedef __attribute__((ext_vector_type(2)))  _Float16 f16x2;
typedef __attribute__((ext_vector_type(8)))  _Float16 f16x8;
typedef __attribute__((ext_vector_type(16))) float    f32x16;
typedef uint32_t u32;
typedef __attribute__((ext_vector_type(2))) u32 u32x2;
typedef __attribute__((ext_vector_type(4))) u32 u32x4;

#define MFMA(a, b, c) __builtin_amdgcn_mfma_f32_32x32x16_f16((a), (b), (c), 0, 0, 0)

constexpr int Bc = 65536;
constexpr int Kc = 16;     // experts
constexpr int Hc = 128;
constexpr int Dc = 64;

constexpr int CAP  = 4608;           // slots/expert = mean 4096 + 8.3 sigma
constexpr int SPB  = 32;             // samples per block (1 wave)
constexpr int BPE  = CAP / SPB;      // 144 blocks per expert
constexpr int NBLK = Kc * BPE;       // 2304 fused blocks
constexpr int NXCD = 8;
constexpr int CHUNK = NBLK / NXCD;   // 288 blocks per XCD (= 2 experts)

constexpr int BBW_F16 = 2048 + 3 * 16384;   // backbone weights (f16 elems)
constexpr int HWE_F16 = 3 * 16384 + 8192;   // per-expert head weights

constexpr int PREP_BLKS = 52 + Kc * 56;     // 948 weight-prep blocks

struct Act { f16x8 w[8]; };   // full 128-feature activation, B-fragment form

__device__ __forceinline__ f32x16 zero16() {
    f32x16 z;
#pragma unroll
    for (int i = 0; i < 16; ++i) z[i] = 0.0f;
    return z;
}

// ---------------------------------------------------------------------------
// Epilogue: v = c + bias (+ReLU), pack to f16, redistribute the D-fragment
// (col=sample, row=(r&3)+8*(r>>2)+4*hi) into the two next-layer B-windows
// (k-local = 8*hi + j) via v_permlane32_swap (pure VALU; HW-verified layout
// r13/r16).
// ---------------------------------------------------------------------------
template<bool RELU>
__device__ __forceinline__ void build_windows(
    const f32x16& c, const float4* bq, f16x8& w0, f16x8& w1)
{
    u32 P[8];
#pragma unroll
    for (int g = 0; g < 4; ++g) {
        const float bb[4] = {bq[g].x, bq[g].y, bq[g].z, bq[g].w};
        f16 h[4];
#pragma unroll
        for (int j = 0; j < 4; ++j) {
            float v = c[4 * g + j] + bb[j];
            if (RELU) v = fmaxf(v, 0.0f);
            h[j] = (f16)v;
        }
        f16x2 p0; p0[0] = h[0]; p0[1] = h[1];
        f16x2 p1; p1[0] = h[2]; p1[1] = h[3];
        P[2 * g]     = __builtin_bit_cast(u32, p0);
        P[2 * g + 1] = __builtin_bit_cast(u32, p1);
    }
    const u32x2 r02 = __builtin_amdgcn_permlane32_swap(P[0], P[2], false, false);
    const u32x2 r13 = __builtin_amdgcn_permlane32_swap(P[1], P[3], false, false);
    const u32x2 r46 = __builtin_amdgcn_permlane32_swap(P[4], P[6], false, false);
    const u32x2 r57 = __builtin_amdgcn_permlane32_swap(P[5], P[7], false, false);
    u32x4 W0 = { r02[0], r13[0], r02[1], r13[1] };
    u32x4 W1 = { r46[0], r57[0], r46[1], r57[1] };
    w0 = __builtin_bit_cast(f16x8, W0);
    w1 = __builtin_bit_cast(f16x8, W1);
}

// ---------------------------------------------------------------------------
// One 128->128 Linear+ReLU layer, weights streamed straight from global
// (L2-resident; layout == consumption order). 8 MFMAs/quarter in two
// chains; compiler pipelines the 32 independent b128 loads across quarters.
// ---------------------------------------------------------------------------
__device__ __forceinline__ void layer_glb(
    const f16* __restrict__ gW, const float* __restrict__ biasG,
    const Act& src, Act& dst, int lane, int bh)
{
#pragma unroll
    for (int q = 0; q < 4; ++q) {
        const f16* pw = gW + q * 4096 + lane * 8;
        float4 bq[4];
#pragma unroll
        for (int g = 0; g < 4; ++g)
            bq[g] = *(const float4*)(biasG + 32 * q + 8 * g + 4 * bh);

        f32x16 c0 = zero16(), c1 = zero16();
        __builtin_amdgcn_s_setprio(1);
#pragma unroll
        for (int ks = 0; ks < 8; ++ks) {
            const f16x8 wh = *(const f16x8*)(pw + ks * 512);
            if (ks & 1) c1 = MFMA(wh, src.w[ks], c1);
            else        c0 = MFMA(wh, src.w[ks], c0);
        }
        __builtin_amdgcn_s_setprio(0);
        const f32x16 cs = c0 + c1;
        build_windows<true>(cs, bq, dst.w[2 * q], dst.w[2 * q + 1]);
    }
}

// ---------------------------------------------------------------------------
// Final 128->64 layer (no ReLU): 2 quarters from global, store to out.
// Lane stores its sample's 16 features per quarter (partner lane with the
// other bh stores the remaining 16): float4 at out[b*64 + 32q + 8g + 4bh].
// ---------------------------------------------------------------------------
__device__ __forceinline__ void layer_final(
    const f16* __restrict__ gW, const float* __restrict__ biasG,
    const Act& src, float* __restrict__ out, int bidx, int lane, int bh)
{
#pragma unroll
    for (int q = 0; q < 2; ++q) {
        const f16* pw = gW + q * 4096 + lane * 8;
        float4 bq[4];
#pragma unroll
        for (int g = 0; g < 4; ++g)
            bq[g] = *(const float4*)(biasG + 32 * q + 8 * g + 4 * bh);

        f32x16 c0 = zero16(), c1 = zero16();
        __builtin_amdgcn_s_setprio(1);
#pragma unroll
        for (int ks = 0; ks < 8; ++ks) {
            const f16x8 wh = *(const f16x8*)(pw + ks * 512);
            if (ks & 1) c1 = MFMA(wh, src.w[ks], c1);
            else        c0 = MFMA(wh, src.w[ks], c0);
        }
        __builtin_amdgcn_s_setprio(0);
        if (bidx >= 0) {
            const f32x16 cs = c0 + c1;
#pragma unroll
            for (int g = 0; g < 4; ++g) {
                float4 v;
                v.x = cs[4 * g + 0] + bq[g].x;
                v.y = cs[4 * g + 1] + bq[g].y;
                v.z = cs[4 * g + 2] + bq[g].z;
                v.w = cs[4 * g + 3] + bq[g].w;
                *(float4*)(out + (size_t)bidx * Dc + 32 * q + 8 * g + 4 * bh) = v;
            }
        }
    }
}

// ---------------------------------------------------------------------------
// Fused MLP: ONE WAVE per block, 32 samples of one expert, end-to-end in
// registers; weights streamed from L2. No LDS, no barriers, no races.
// ---------------------------------------------------------------------------
__global__ __launch_bounds__(64, 2) void fused_mlp(
    const float* __restrict__ z,
    const int* __restrict__ idxb, const int* __restrict__ cursor,
    const f16* __restrict__ bbW,
    const float* __restrict__ bb0, const float* __restrict__ bb1,
    const float* __restrict__ bb2, const float* __restrict__ bb3,
    const f16* __restrict__ hW,
    const float* __restrict__ hb0, const float* __restrict__ hb1,
    const float* __restrict__ hb2, const float* __restrict__ hb3,
    float* __restrict__ out)
{
    // XCD-chunked bijective swizzle (NBLK % 8 == 0).
    const int blk = (blockIdx.x % NXCD) * CHUNK + blockIdx.x / NXCD;
    const int e = blk / BPE;
    const int local0 = (blk % BPE) * SPB;
    const int cnt = min(cursor[e * 16], CAP);
    if (cnt - local0 <= 0) return;

    const int lane = threadIdx.x & 63;
    const int l31 = lane & 31, bh = lane >> 5;

    // ---- sample index + z gather -> layer0 act window (k=16) ----
    int bidx = -1;
    const int sIdx = local0 + l31;
    if (sIdx < cnt) bidx = idxb[e * CAP + sIdx];

    f16x8 zw;
    if (bidx >= 0) {
        const float4 u0 = *(const float4*)(z + (size_t)bidx * 16 + bh * 8);
        const float4 u1 = *(const float4*)(z + (size_t)bidx * 16 + bh * 8 + 4);
        zw[0] = (f16)u0.x; zw[1] = (f16)u0.y; zw[2] = (f16)u0.z; zw[3] = (f16)u0.w;
        zw[4] = (f16)u1.x; zw[5] = (f16)u1.y; zw[6] = (f16)u1.z; zw[7] = (f16)u1.w;
    } else {
#pragma unroll
        for (int j = 0; j < 8; ++j) zw[j] = (f16)0.0f;
    }

    Act aA, aB;
    // layer0 (16->128): K=16, one MFMA per quarter
#pragma unroll
    for (int q = 0; q < 4; ++q) {
        float4 bq[4];
#pragma unroll
        for (int g = 0; g < 4; ++g)
            bq[g] = *(const float4*)(bb0 + 32 * q + 8 * g + 4 * bh);
        const f16x8 wh = *(const f16x8*)(bbW + q * 512 + lane * 8);
        f32x16 c0 = zero16();
        c0 = MFMA(wh, zw, c0);
        build_windows<true>(c0, bq, aA.w[2 * q], aA.w[2 * q + 1]);
    }

    // backbone layers 1-3, head layers 0-2, final
    const size_t we = (size_t)e * HWE_F16;
    layer_glb(bbW + 2048,      bb1,          aA, aB, lane, bh);
    layer_glb(bbW + 18432,     bb2,          aB, aA, lane, bh);
    layer_glb(bbW + 34816,     bb3,          aA, aB, lane, bh);
    layer_glb(hW + we,         hb0 + e * Hc, aB, aA, lane, bh);
    layer_glb(hW + we + 16384, hb1 + e * Hc, aA, aB, lane, bh);
    layer_glb(hW + we + 32768, hb2 + e * Hc, aB, aA, lane, bh);
    layer_final(hW + we + 49152, hb3 + e * Dc, aA, out, bidx, lane, bh);
}

// ---------------------------------------------------------------------------
// prep_w + scatter in one kernel (disjoint block ranges; scatter blocks only
// touch y/idxb/cursor, cursor pre-zeroed by hipMemsetAsync).
// Weight prep: fp32 W[k][n] -> single f16, transposed and re-laid per
// 32-row chunk as [ks][lane] (layout unchanged from r19).
// ---------------------------------------------------------------------------
__global__ void prep_scatter(
    const float* __restrict__ bw0, const float* __restrict__ bw1,
    const float* __restrict__ bw2, const float* __restrict__ bw3,
    const float* __restrict__ hw0, const float* __restrict__ hw1,
    const float* __restrict__ hw2, const float* __restrict__ hw3,
    f16* __restrict__ bbW, f16* __restrict__ hW,
    const int* __restrict__ y, int* __restrict__ idxb, int* __restrict__ cursor)
{
    __shared__ float T[32][33];
    __shared__ int lc[Kc];
    __shared__ int lbase[Kc];
    const int id = blockIdx.x;
    const int tx = threadIdx.x;

    if (id >= PREP_BLKS) {
        // ---- scatter block ----
        if (tx < Kc) lc[tx] = 0;
        __syncthreads();
        const int b = (id - PREP_BLKS) * 256 + tx;
        const int e = y[b];
        const int r = atomicAdd(&lc[e], 1);
        __syncthreads();
        if (tx < Kc) lbase[tx] = atomicAdd(&cursor[tx * 16], lc[tx]);
        __syncthreads();
        const int slot = lbase[e] + r;
        if (slot < CAP) idxb[e * CAP + slot] = b;
        return;
    }

    // ---- weight-prep block ----
    const float* src; f16 *dh;
    int K, N, k0, n0;
    bool big;

    if (id < 52) {
        if (id < 4) {
            src = bw0; dh = bbW;
            K = 16; N = 128; k0 = 0; n0 = id * 32; big = false;
        } else {
            const int t = id - 4;
            const int l = t / 16, tile = t % 16;
            const float* bws[3] = {bw1, bw2, bw3};
            src = bws[l];
            dh = bbW + 2048 + l * 16384;
            K = 128; N = 128; big = true;
            k0 = (tile >> 2) * 32; n0 = (tile & 3) * 32;
        }
    } else {
        const int t = id - 52;
        const int e = t / 56, r = t % 56;
        if (r < 48) {
            const int l = r / 16, tile = r % 16;
            const float* hws[3] = {hw0, hw1, hw2};
            src = hws[l] + (size_t)e * 16384;
            dh = hW + (size_t)e * HWE_F16 + l * 16384;
            K = 128; N = 128; big = true;
            k0 = (tile >> 2) * 32; n0 = (tile & 3) * 32;
        } else {
            const int r2 = r - 48;
            src = hw3 + (size_t)e * 8192;
            dh = hW + (size_t)e * HWE_F16 + 49152;
            K = 128; N = 64; big = true;
            k0 = (r2 >> 1) * 32; n0 = (r2 & 1) * 32;
        }
    }

    const int c = tx & 31, g = tx >> 5;
#pragma unroll
    for (int i = 0; i < 4; ++i) {
        const int row = g * 4 + i;
        if (k0 + row < K)
            T[c][row] = src[(size_t)(k0 + row) * N + n0 + c];   // T[n-local][k-local]
    }
    __syncthreads();
#pragma unroll
    for (int i = 0; i < 4; ++i) {
        const int n = n0 + g * 4 + i;
        const int k = k0 + c;
        if (k < K) {
            const float v = T[g * 4 + i][c];
            size_t didx;
            if (big)
                didx = (size_t)(n >> 5) * 4096 + (size_t)(k >> 4) * 512
                     + ((k >> 3) & 1) * 256 + (n & 31) * 8 + (k & 7);
            else
                didx = (size_t)(n >> 5) * 512 + (size_t)(k >> 3) * 256
                     + (n & 31) * 8 + (k & 7);
            dh[didx] = (f16)v;
        }
    }
}

// ---------------------------------------------------------------------------
extern "C" void kernel_launch(void* const* d_in, const int* in_sizes, int n_in,
                              void* d_out, int out_size, void* d_ws, size_t ws_size,
                              hipStream_t stream)
{
    const float* z   = (const float*)d_in[0];
    const int*   y   = (const int*)d_in[1];
    const float* bw0 = (const float*)d_in[2];
    const float* bb0 = (const float*)d_in[3];
    const float* bw1 = (const float*)d_in[4];
    const float* bb1 = (const float*)d_in[5];
    const float* bw2 = (const float*)d_in[6];
    const float* bb2 = (const float*)d_in[7];
    const float* bw3 = (const float*)d_in[8];
    const float* bb3 = (const float*)d_in[9];
    const float* hw0 = (const float*)d_in[10];
    const float* hb0 = (const float*)d_in[11];
    const float* hw1 = (const float*)d_in[12];
    const float* hb1 = (const float*)d_in[13];
    const float* hw2 = (const float*)d_in[14];
    const float* hb2 = (const float*)d_in[15];
    const float* hw3 = (const float*)d_in[16];
    const float* hb3 = (const float*)d_in[17];
    float* out = (float*)d_out;

    // workspace layout (segments 256B-aligned)
    char* p = (char*)d_ws;
    f16* bbW = (f16*)p;  p += (size_t)BBW_F16 * 2;
    f16* hW  = (f16*)p;  p += (size_t)Kc * HWE_F16 * 2;
    int* idxb = (int*)p; p += (size_t)Kc * CAP * 4;
    int* cursor = (int*)p;                                   // 256 ints, padded

    hipMemsetAsync(cursor, 0, 256 * sizeof(int), stream);

    prep_scatter<<<PREP_BLKS + Bc / 256, 256, 0, stream>>>(
        bw0, bw1, bw2, bw3, hw0, hw1, hw2, hw3,
        bbW, hW, y, idxb, cursor);

    fused_mlp<<<NBLK, 64, 0, stream>>>(
        z, idxb, cursor, bbW, bb0, bb1, bb2, bb3,
        hW, hb0, hb1, hb2, hb3, out);
}

// Round 12
// 130.778 us; speedup vs baseline: 1.0590x; 1.0590x over previous
//
#include <hip/hip_runtime.h>
#include <hip/hip_bf16.h>
#include <stdint.h>

// ---------------------------------------------------------------------------
// MappingNetwork: backbone 4x(Linear+ReLU) [16->128, 3x 128->128], then the
// selected expert head only (4 layers, last no-ReLU, 128->64).
//
// Round-22: WAVE-PRIVATE LDS PIPELINE (r21 independence + r19 async
// prefetch, ZERO barriers). r21 post-mortem: L2-direct regressed to ~50us
// (MfmaUtil 10.5, VGPR 68) -- compiler gave no prefetch depth, so each
// quarter ate a bare ~200-400cyc L2 latency; 9 waves/CU TLP can't cover it.
// r19's LDS staging was valuable as an EXPLICIT ASYNC PREFETCH BUFFER, not
// for bandwidth. Fix: 1-wave blocks (64 thr, 32 samples, NBLK=2304, 9
// blocks/CU; cross-wave race surface structurally zero) each own a PRIVATE
// 16KB LDS dbuf (2 x 8KB quarter), paced by the wave's own vmcnt:
//   per global quarter g: s_waitcnt vmcnt(8)  [= keep only the newest 8 ops
//   (the last stage) in flight; bias/store ops are absorbed by FIFO count
//   since stage is always issued LAST] -> sched_barrier(0) (rule 18) ->
//   ds_read + 8 MFMA + epilogue -> stage quarter g+2 into the slot just
//   read (WAR-safe by intra-wave program order; ~1 compute phase ~450cyc
//   covers L2 latency). Slot parity = g&1 (4 quarters/layer keeps it
//   consistent; head-L2's q=2,3 stage the final layer's 2 quarters).
//
// Kept from r19/r21 (verified): single-term f16 weights (absmax 1.5259e-5,
// 4x margin vs 6.226e-5); M=32/wave acts-in-registers; 16B global_load_lds,
// memory layout == consumption order (conflict-free b128); permlane32_swap
// epilogue (HW-verified D->B layouts); setprio around MFMA (independent-
// wave regime); XCD-chunked bijective swizzle (2304%8==0); CAP=4608 idxb;
// prep_scatter unchanged.
// ---------------------------------------------------------------------------

typedef _Float16 f16;
typedef __attribute__((ext_vector_type(2)))  _Float16 f16x2;
typedef __attribute__((ext_vector_type(8)))  _Float16 f16x8;
typedef __attribute__((ext_vector_type(16))) float    f32x16;
typedef uint32_t u32;
typedef __attribute__((ext_vector_type(2))) u32 u32x2;
typedef __attribute__((ext_vector_type(4))) u32 u32x4;

#define MFMA(a, b, c) __builtin_amdgcn_mfma_f32_32x32x16_f16((a), (b), (c), 0, 0, 0)

constexpr int Bc = 65536;
constexpr int Kc = 16;     // experts
constexpr int Hc = 128;
constexpr int Dc = 64;

constexpr int CAP  = 4608;           // slots/expert = mean 4096 + 8.3 sigma
constexpr int SPB  = 32;             // samples per block (1 wave)
constexpr int BPE  = CAP / SPB;      // 144 blocks per expert
constexpr int NBLK = Kc * BPE;       // 2304 fused blocks
constexpr int NXCD = 8;
constexpr int CHUNK = NBLK / NXCD;   // 288 blocks per XCD (= 2 experts)

constexpr int BBW_F16 = 2048 + 3 * 16384;   // backbone weights (f16 elems)
constexpr int HWE_F16 = 3 * 16384 + 8192;   // per-expert head weights

constexpr int PREP_BLKS = 52 + Kc * 56;     // 948 weight-prep blocks

struct Act { f16x8 w[8]; };   // full 128-feature activation, B-fragment form

__device__ __forceinline__ f32x16 zero16() {
    f32x16 z;
#pragma unroll
    for (int i = 0; i < 16; ++i) z[i] = 0.0f;
    return z;
}

// async global->LDS, 16B per lane; LDS base wave-uniform.
__device__ __forceinline__ void gload16(const f16* g, f16* l) {
    __builtin_amdgcn_global_load_lds(
        (const __attribute__((address_space(1))) void*)g,
        (__attribute__((address_space(3))) void*)l, 16, 0, 0);
}

// Stage one full 32-feature quarter (8KB = 4096 f16) by ONE wave:
// exactly 8 gload16 (1KB each). The vmcnt(8) pacing depends on this count.
__device__ __forceinline__ void stage_q(f16* dst, const f16* gW, int lane) {
#pragma unroll
    for (int i = 0; i < 8; ++i)
        gload16(gW + i * 512 + lane * 8, dst + i * 512);
}

// Pipeline wait: everything except the newest 8 vmem ops (= the last stage)
// has completed. sched_barrier pins following ds_reads below (rule 18).
__device__ __forceinline__ void pipe_wait() {
    asm volatile("s_waitcnt vmcnt(8)" ::: "memory");
    __builtin_amdgcn_sched_barrier(0);
}

// ---------------------------------------------------------------------------
// Epilogue: v = c + bias (+ReLU), pack to f16, redistribute the D-fragment
// (col=sample, row=(r&3)+8*(r>>2)+4*hi) into the two next-layer B-windows
// (k-local = 8*hi + j) via v_permlane32_swap (pure VALU; HW-verified layout
// r13/r16).
// ---------------------------------------------------------------------------
template<bool RELU>
__device__ __forceinline__ void build_windows(
    const f32x16& c, const float4* bq, f16x8& w0, f16x8& w1)
{
    u32 P[8];
#pragma unroll
    for (int g = 0; g < 4; ++g) {
        const float bb[4] = {bq[g].x, bq[g].y, bq[g].z, bq[g].w};
        f16 h[4];
#pragma unroll
        for (int j = 0; j < 4; ++j) {
            float v = c[4 * g + j] + bb[j];
            if (RELU) v = fmaxf(v, 0.0f);
            h[j] = (f16)v;
        }
        f16x2 p0; p0[0] = h[0]; p0[1] = h[1];
        f16x2 p1; p1[0] = h[2]; p1[1] = h[3];
        P[2 * g]     = __builtin_bit_cast(u32, p0);
        P[2 * g + 1] = __builtin_bit_cast(u32, p1);
    }
    const u32x2 r02 = __builtin_amdgcn_permlane32_swap(P[0], P[2], false, false);
    const u32x2 r13 = __builtin_amdgcn_permlane32_swap(P[1], P[3], false, false);
    const u32x2 r46 = __builtin_amdgcn_permlane32_swap(P[4], P[6], false, false);
    const u32x2 r57 = __builtin_amdgcn_permlane32_swap(P[5], P[7], false, false);
    u32x4 W0 = { r02[0], r13[0], r02[1], r13[1] };
    u32x4 W1 = { r46[0], r57[0], r46[1], r57[1] };
    w0 = __builtin_bit_cast(f16x8, W0);
    w1 = __builtin_bit_cast(f16x8, W1);
}

// ---------------------------------------------------------------------------
// One 128->128 Linear+ReLU layer = 4 pipelined quarters from the wave's
// private LDS dbuf. q<2 stages cur layer q+2; q>=2 stages next layer q-2.
// Stage is issued LAST (after all reads of that slot) -- intra-wave WAR-safe.
// ---------------------------------------------------------------------------
__device__ __forceinline__ void layer_pipe(
    f16* lds, const Act& src, Act& dst,
    const f16* __restrict__ gW, const f16* __restrict__ gWN,
    const float* __restrict__ biasG, int lane, int bh)
{
#pragma unroll
    for (int q = 0; q < 4; ++q) {
        pipe_wait();

        float4 bq[4];
#pragma unroll
        for (int g = 0; g < 4; ++g)
            bq[g] = *(const float4*)(biasG + 32 * q + 8 * g + 4 * bh);

        const f16* pw = lds + (q & 1) * 4096 + lane * 8;
        f32x16 c0 = zero16(), c1 = zero16();
        __builtin_amdgcn_s_setprio(1);
#pragma unroll
        for (int ks = 0; ks < 8; ++ks) {
            const f16x8 wh = *(const f16x8*)(pw + ks * 512);
            if (ks & 1) c1 = MFMA(wh, src.w[ks], c1);
            else        c0 = MFMA(wh, src.w[ks], c0);
        }
        __builtin_amdgcn_s_setprio(0);
        const f32x16 cs = c0 + c1;
        build_windows<true>(cs, bq, dst.w[2 * q], dst.w[2 * q + 1]);

        __builtin_amdgcn_sched_barrier(0);   // keep stage below all slot reads
        if (q < 2) stage_q(lds + (q & 1) * 4096, gW  + (q + 2) * 4096, lane);
        else       stage_q(lds + (q & 1) * 4096, gWN + (q - 2) * 4096, lane);
    }
}

// ---------------------------------------------------------------------------
// Final 128->64 layer (no ReLU): 2 quarters (pre-staged by head-L2's q=2,3),
// store straight to out: float4 at out[b*64 + 32q + 8g + 4bh].
// ---------------------------------------------------------------------------
__device__ __forceinline__ void layer_final(
    const f16* lds, const Act& src, const float* __restrict__ biasG,
    float* __restrict__ out, int bidx, int lane, int bh)
{
#pragma unroll
    for (int q = 0; q < 2; ++q) {
        pipe_wait();

        float4 bq[4];
#pragma unroll
        for (int g = 0; g < 4; ++g)
            bq[g] = *(const float4*)(biasG + 32 * q + 8 * g + 4 * bh);

        const f16* pw = lds + (q & 1) * 4096 + lane * 8;
        f32x16 c0 = zero16(), c1 = zero16();
        __builtin_amdgcn_s_setprio(1);
#pragma unroll
        for (int ks = 0; ks < 8; ++ks) {
            const f16x8 wh = *(const f16x8*)(pw + ks * 512);
            if (ks & 1) c1 = MFMA(wh, src.w[ks], c1);
            else        c0 = MFMA(wh, src.w[ks], c0);
        }
        __builtin_amdgcn_s_setprio(0);
        if (bidx >= 0) {
            const f32x16 cs = c0 + c1;
#pragma unroll
            for (int g = 0; g < 4; ++g) {
                float4 v;
                v.x = cs[4 * g + 0] + bq[g].x;
                v.y = cs[4 * g + 1] + bq[g].y;
                v.z = cs[4 * g + 2] + bq[g].z;
                v.w = cs[4 * g + 3] + bq[g].w;
                *(float4*)(out + (size_t)bidx * Dc + 32 * q + 8 * g + 4 * bh) = v;
            }
        }
    }
}

// ---------------------------------------------------------------------------
// Fused MLP: ONE WAVE per block, 32 samples of one expert, acts in registers
// end-to-end; weights async-staged through a wave-private 16KB LDS dbuf.
// No __syncthreads anywhere; sync = the wave's own vmcnt only.
// ---------------------------------------------------------------------------
__global__ __launch_bounds__(64, 2) void fused_mlp(
    const float* __restrict__ z,
    const int* __restrict__ idxb, const int* __restrict__ cursor,
    const f16* __restrict__ bbW,
    const float* __restrict__ bb0, const float* __restrict__ bb1,
    const float* __restrict__ bb2, const float* __restrict__ bb3,
    const f16* __restrict__ hW,
    const float* __restrict__ hb0, const float* __restrict__ hb1,
    const float* __restrict__ hb2, const float* __restrict__ hb3,
    float* __restrict__ out)
{
    __shared__ __attribute__((aligned(16))) f16 WLDS[2 * 4096];   // 16KB

    // XCD-chunked bijective swizzle (NBLK % 8 == 0).
    const int blk = (blockIdx.x % NXCD) * CHUNK + blockIdx.x / NXCD;
    const int e = blk / BPE;
    const int local0 = (blk % BPE) * SPB;
    const int cnt = min(cursor[e * 16], CAP);
    if (cnt - local0 <= 0) return;

    const int lane = threadIdx.x & 63;
    const int l31 = lane & 31, bh = lane >> 5;

    // ---- sample index + z gather -> layer0 act window (k=16) ----
    int bidx = -1;
    const int sIdx = local0 + l31;
    if (sIdx < cnt) bidx = idxb[e * CAP + sIdx];

    f16x8 zw;
    if (bidx >= 0) {
        const float4 u0 = *(const float4*)(z + (size_t)bidx * 16 + bh * 8);
        const float4 u1 = *(const float4*)(z + (size_t)bidx * 16 + bh * 8 + 4);
        zw[0] = (f16)u0.x; zw[1] = (f16)u0.y; zw[2] = (f16)u0.z; zw[3] = (f16)u0.w;
        zw[4] = (f16)u1.x; zw[5] = (f16)u1.y; zw[6] = (f16)u1.z; zw[7] = (f16)u1.w;
    } else {
#pragma unroll
        for (int j = 0; j < 8; ++j) zw[j] = (f16)0.0f;
    }

    // ---- prologue: stage L1 q0 -> slot0, L1 q1 -> slot1 (16 ops in flight);
    // they overlap the layer0 compute below. First pipe_wait drains both
    // (they are older than L0's VGPR loads).
    stage_q(WLDS,        bbW + 2048,        lane);
    stage_q(WLDS + 4096, bbW + 2048 + 4096, lane);

    Act aA, aB;
    // layer0 (16->128): K=16, W0 tiny (4KB), read per-wave from global.
#pragma unroll
    for (int q = 0; q < 4; ++q) {
        float4 bq[4];
#pragma unroll
        for (int g = 0; g < 4; ++g)
            bq[g] = *(const float4*)(bb0 + 32 * q + 8 * g + 4 * bh);
        const f16x8 wh = *(const f16x8*)(bbW + q * 512 + lane * 8);
        f32x16 c0 = zero16();
        c0 = MFMA(wh, zw, c0);
        build_windows<true>(c0, bq, aA.w[2 * q], aA.w[2 * q + 1]);
    }

    // ---- 6 pipelined layers + final (global quarter parity == q&1) ----
    const size_t we = (size_t)e * HWE_F16;
    layer_pipe(WLDS, aA, aB, bbW + 2048,      bbW + 18432,     bb1, lane, bh);
    layer_pipe(WLDS, aB, aA, bbW + 18432,     bbW + 34816,     bb2, lane, bh);
    layer_pipe(WLDS, aA, aB, bbW + 34816,     hW + we,         bb3, lane, bh);
    layer_pipe(WLDS, aB, aA, hW + we,         hW + we + 16384, hb0 + e * Hc, lane, bh);
    layer_pipe(WLDS, aA, aB, hW + we + 16384, hW + we + 32768, hb1 + e * Hc, lane, bh);
    layer_pipe(WLDS, aB, aA, hW + we + 32768, hW + we + 49152, hb2 + e * Hc, lane, bh);
    layer_final(WLDS, aA, hb3 + e * Dc, out, bidx, lane, bh);
}

// ---------------------------------------------------------------------------
// prep_w + scatter in one kernel (disjoint block ranges; scatter blocks only
// touch y/idxb/cursor, cursor pre-zeroed by hipMemsetAsync).
// Weight prep: fp32 W[k][n] -> single f16, transposed and re-laid per
// 32-row chunk as [ks][lane] (layout unchanged from r19).
// ---------------------------------------------------------------------------
__global__ void prep_scatter(
    const float* __restrict__ bw0, const float* __restrict__ bw1,
    const float* __restrict__ bw2, const float* __restrict__ bw3,
    const float* __restrict__ hw0, const float* __restrict__ hw1,
    const float* __restrict__ hw2, const float* __restrict__ hw3,
    f16* __restrict__ bbW, f16* __restrict__ hW,
    const int* __restrict__ y, int* __restrict__ idxb, int* __restrict__ cursor)
{
    __shared__ float T[32][33];
    __shared__ int lc[Kc];
    __shared__ int lbase[Kc];
    const int id = blockIdx.x;
    const int tx = threadIdx.x;

    if (id >= PREP_BLKS) {
        // ---- scatter block ----
        if (tx < Kc) lc[tx] = 0;
        __syncthreads();
        const int b = (id - PREP_BLKS) * 256 + tx;
        const int e = y[b];
        const int r = atomicAdd(&lc[e], 1);
        __syncthreads();
        if (tx < Kc) lbase[tx] = atomicAdd(&cursor[tx * 16], lc[tx]);
        __syncthreads();
        const int slot = lbase[e] + r;
        if (slot < CAP) idxb[e * CAP + slot] = b;
        return;
    }

    // ---- weight-prep block ----
    const float* src; f16 *dh;
    int K, N, k0, n0;
    bool big;

    if (id < 52) {
        if (id < 4) {
            src = bw0; dh = bbW;
            K = 16; N = 128; k0 = 0; n0 = id * 32; big = false;
        } else {
            const int t = id - 4;
            const int l = t / 16, tile = t % 16;
            const float* bws[3] = {bw1, bw2, bw3};
            src = bws[l];
            dh = bbW + 2048 + l * 16384;
            K = 128; N = 128; big = true;
            k0 = (tile >> 2) * 32; n0 = (tile & 3) * 32;
        }
    } else {
        const int t = id - 52;
        const int e = t / 56, r = t % 56;
        if (r < 48) {
            const int l = r / 16, tile = r % 16;
            const float* hws[3] = {hw0, hw1, hw2};
            src = hws[l] + (size_t)e * 16384;
            dh = hW + (size_t)e * HWE_F16 + l * 16384;
            K = 128; N = 128; big = true;
            k0 = (tile >> 2) * 32; n0 = (tile & 3) * 32;
        } else {
            const int r2 = r - 48;
            src = hw3 + (size_t)e * 8192;
            dh = hW + (size_t)e * HWE_F16 + 49152;
            K = 128; N = 64; big = true;
            k0 = (r2 >> 1) * 32; n0 = (r2 & 1) * 32;
        }
    }

    const int c = tx & 31, g = tx >> 5;
#pragma unroll
    for (int i = 0; i < 4; ++i) {
        const int row = g * 4 + i;
        if (k0 + row < K)
            T[c][row] = src[(size_t)(k0 + row) * N + n0 + c];   // T[n-local][k-local]
    }
    __syncthreads();
#pragma unroll
    for (int i = 0; i < 4; ++i) {
        const int n = n0 + g * 4 + i;
        const int k = k0 + c;
        if (k < K) {
            const float v = T[g * 4 + i][c];
            size_t didx;
            if (big)
                didx = (size_t)(n >> 5) * 4096 + (size_t)(k >> 4) * 512
                     + ((k >> 3) & 1) * 256 + (n & 31) * 8 + (k & 7);
            else
                didx = (size_t)(n >> 5) * 512 + (size_t)(k >> 3) * 256
                     + (n & 31) * 8 + (k & 7);
            dh[didx] = (f16)v;
        }
    }
}

// ---------------------------------------------------------------------------
extern "C" void kernel_launch(void* const* d_in, const int* in_sizes, int n_in,
                              void* d_out, int out_size, void* d_ws, size_t ws_size,
                              hipStream_t stream)
{
    const float* z   = (const float*)d_in[0];
    const int*   y   = (const int*)d_in[1];
    const float* bw0 = (const float*)d_in[2];
    const float* bb0 = (const float*)d_in[3];
    const float* bw1 = (const float*)d_in[4];
    const float* bb1 = (const float*)d_in[5];
    const float* bw2 = (const float*)d_in[6];
    const float* bb2 = (const float*)d_in[7];
    const float* bw3 = (const float*)d_in[8];
    const float* bb3 = (const float*)d_in[9];
    const float* hw0 = (const float*)d_in[10];
    const float* hb0 = (const float*)d_in[11];
    const float* hw1 = (const float*)d_in[12];
    const float* hb1 = (const float*)d_in[13];
    const float* hw2 = (const float*)d_in[14];
    const float* hb2 = (const float*)d_in[15];
    const float* hw3 = (const float*)d_in[16];
    const float* hb3 = (const float*)d_in[17];
    float* out = (float*)d_out;

    // workspace layout (segments 256B-aligned)
    char* p = (char*)d_ws;
    f16* bbW = (f16*)p;  p += (size_t)BBW_F16 * 2;
    f16* hW  = (f16*)p;  p += (size_t)Kc * HWE_F16 * 2;
    int* idxb = (int*)p; p += (size_t)Kc * CAP * 4;
    int* cursor = (int*)p;                                   // 256 ints, padded

    hipMemsetAsync(cursor, 0, 256 * sizeof(int), stream);

    prep_scatter<<<PREP_BLKS + Bc / 256, 256, 0, stream>>>(
        bw0, bw1, bw2, bw3, hw0, hw1, hw2, hw3,
        bbW, hW, y, idxb, cursor);

    fused_mlp<<<NBLK, 64, 0, stream>>>(
        z, idxb, cursor, bbW, bb0, bb1, bb2, bb3,
        hW, hb0, hb1, hb2, hb3, out);
}